// Round 1
// baseline (106.453 us; speedup 1.0000x reference)
//
#include <hip/hip_runtime.h>
#include <stdint.h>

// Problem constants (match reference setup_inputs)
#define BB   16
#define CC   64
#define LL   8192
#define OO   64
#define KK   3
#define TT   64        // positions per block tile
#define XSW  72        // xs LDS stride (bf16 elems); 67 used, pad for banks + 16B align
#define SW   200       // S / Wt LDS stride (bf16 elems); 192 used, pad breaks 16-lane clash

typedef __attribute__((ext_vector_type(8))) short short8;     // 8 bf16 = 4 VGPRs (MFMA A/B frag)
typedef __attribute__((ext_vector_type(4))) float float4_t;   // MFMA C/D frag

__device__ __forceinline__ ushort f2bf(float f) {
    uint32_t u = __float_as_uint(f);
    return (ushort)((u + 0x7FFFu + ((u >> 16) & 1u)) >> 16);  // RNE
}
__device__ __forceinline__ float bf2f(ushort h) {
    return __uint_as_float(((uint32_t)h) << 16);
}

// Pre-kernel: weight [O][C][K] fp32 -> wt [O][K*64 + c] bf16 (row-major over ck=k*64+c)
__global__ void wt_prep(const float* __restrict__ w, ushort* __restrict__ wt) {
    int idx = blockIdx.x * 256 + threadIdx.x;
    if (idx < OO * CC * KK) {
        int f = idx / (CC * KK);
        int rem = idx - f * (CC * KK);
        int c = rem / KK;
        int k = rem - c * KK;
        wt[f * (KK * CC) + k * CC + c] = f2bf(w[idx]);
    }
}

__global__ __launch_bounds__(256, 2) void deform_main(
    const float* __restrict__ x, const float* __restrict__ offs,
    const ushort* __restrict__ wt, const float* __restrict__ bias,
    float* __restrict__ out) {

    __shared__ ushort xs[67 * XSW];       // x tile, [pos][c], bf16
    __shared__ ushort S[TT * SW];         // sampled, [n][k*64+c], bf16
    __shared__ ushort Wt[OO * SW];        // weight, [f][k*64+c], bf16
    __shared__ int    Ul[TT * KK];        // local floor index per (n,k)
    __shared__ float  W0s[TT * KK], W1s[TT * KK];

    const int tid  = threadIdx.x;
    const int bb   = blockIdx.x >> 7;     // / (LL/TT = 128)
    const int tile = blockIdx.x & 127;
    const int ts   = tile * TT;

    // ---- Phase 1a: weight -> LDS (1536 uint4 = 12288 bf16) ----
    {
        const uint4* src = (const uint4*)wt;
        #pragma unroll
        for (int i = 0; i < 6; i++) {
            int idx = tid + i * 256;       // uint4 index (8 bf16 each)
            int e0  = idx * 8;
            int row = e0 / 192;
            int col = e0 - row * 192;      // multiple of 8, never straddles a row
            *(uint4*)&Wt[row * SW + col] = src[idx];
        }
    }

    // ---- Phase 1b: x tile -> LDS (transposed, bf16). padded pos p = ts+i, i in [0,67) ----
    {
        const float* xb = x + (size_t)bb * (CC * LL);
        #pragma unroll
        for (int i = 0; i < 17; i++) {
            int idx = tid + i * 256;
            if (idx < 64 * 67) {
                int c = idx / 67;
                int p = idx - c * 67;
                int j = ts + p - 1;                 // unpadded index, reflect at edges
                if (j < 0) j = -j;
                if (j >= LL) j = 2 * LL - 2 - j;
                xs[p * XSW + c] = f2bf(xb[c * LL + j]);
            }
        }
    }

    // ---- Phase 1c: offsets -> (U, w0, w1) per (n,k) ----
    if (tid < TT * KK) {
        int n = tid / 3;
        int k = tid - n * 3;
        float off = offs[((size_t)bb * LL + ts + n) * 3 + k];
        float t0  = (float)(ts + n);
        float T   = t0 + (float)k + off;
        T = fmaxf(T, t0);
        T = fminf(T, t0 + 2.0f);
        int U = (int)floorf(T);
        if (U > LL) U = LL;                 // clip to Lp-2 = 8192
        float Uf = (float)U;
        float w0 = fmaxf(0.0f, 1.0f - fabsf(Uf - T));
        float w1 = fmaxf(0.0f, 1.0f - fabsf(Uf + 1.0f - T));
        Ul[tid]  = U - ts;                  // in [n, n+2] -> xs rows valid
        W0s[tid] = w0;
        W1s[tid] = w1;
    }
    __syncthreads();

    // ---- Phase 2: build S[n][k*64+c] = w0*xs[u][c] + w1*xs[u+1][c], bf16 ----
    // 64n * 3k * 8 c-groups = 1536 tasks
    #pragma unroll
    for (int i = 0; i < 6; i++) {
        int tau = tid + i * 256;
        int g   = tau & 7;
        int nk  = tau >> 3;                 // n*3 + k
        int n   = nk / 3;
        int k   = nk - n * 3;
        int u   = Ul[nk];
        float w0 = W0s[nk], w1 = W1s[nk];
        int c0  = g * 8;
        union { uint4 v; ushort u16[8]; } r0, r1;
        r0.v = *(const uint4*)&xs[u * XSW + c0];
        r1.v = *(const uint4*)&xs[(u + 1) * XSW + c0];
        uint32_t pk[4];
        #pragma unroll
        for (int j = 0; j < 4; j++) {
            float v0 = w0 * bf2f(r0.u16[2 * j])     + w1 * bf2f(r1.u16[2 * j]);
            float v1 = w0 * bf2f(r0.u16[2 * j + 1]) + w1 * bf2f(r1.u16[2 * j + 1]);
            pk[j] = (uint32_t)f2bf(v0) | ((uint32_t)f2bf(v1) << 16);
        }
        uint4 ov;
        ov.x = pk[0]; ov.y = pk[1]; ov.z = pk[2]; ov.w = pk[3];
        *(uint4*)&S[n * SW + k * 64 + c0] = ov;
    }
    __syncthreads();

    // ---- Phase 3: GEMM. wave w: m-tile = f in [16w,16w+16); 4 n-tiles of 16 ----
    const int lane = tid & 63;
    const int wv   = tid >> 6;
    const int lr   = lane & 15;   // m for A-frag, n for B-frag, col for C
    const int q    = lane >> 4;   // k-quad
    float4_t acc0 = {0.f, 0.f, 0.f, 0.f};
    float4_t acc1 = acc0, acc2 = acc0, acc3 = acc0;

    #pragma unroll
    for (int kk = 0; kk < 6; kk++) {
        int k0 = kk * 32 + q * 8;
        short8 a  = *(const short8*)&Wt[(wv * 16 + lr) * SW + k0];
        short8 b0 = *(const short8*)&S[(0 * 16 + lr) * SW + k0];
        short8 b1 = *(const short8*)&S[(1 * 16 + lr) * SW + k0];
        short8 b2 = *(const short8*)&S[(2 * 16 + lr) * SW + k0];
        short8 b3 = *(const short8*)&S[(3 * 16 + lr) * SW + k0];
        acc0 = __builtin_amdgcn_mfma_f32_16x16x32_bf16(a, b0, acc0, 0, 0, 0);
        acc1 = __builtin_amdgcn_mfma_f32_16x16x32_bf16(a, b1, acc1, 0, 0, 0);
        acc2 = __builtin_amdgcn_mfma_f32_16x16x32_bf16(a, b2, acc2, 0, 0, 0);
        acc3 = __builtin_amdgcn_mfma_f32_16x16x32_bf16(a, b3, acc3, 0, 0, 0);
    }

    // ---- Phase 4: epilogue. C/D: col = lane&15 (n), row = q*4 + r (m) ----
    const int f0 = wv * 16 + q * 4;
    float4_t bv = *(const float4_t*)&bias[f0];
    float* ob = out + ((size_t)bb * OO + f0) * LL + ts;
    #pragma unroll
    for (int r = 0; r < 4; r++) {
        float* orow = ob + (size_t)r * LL;
        orow[ 0 + lr] = acc0[r] + bv[r];
        orow[16 + lr] = acc1[r] + bv[r];
        orow[32 + lr] = acc2[r] + bv[r];
        orow[48 + lr] = acc3[r] + bv[r];
    }
}

extern "C" void kernel_launch(void* const* d_in, const int* in_sizes, int n_in,
                              void* d_out, int out_size, void* d_ws, size_t ws_size,
                              hipStream_t stream) {
    const float* x    = (const float*)d_in[0];
    const float* offs = (const float*)d_in[1];
    const float* w    = (const float*)d_in[2];
    const float* bias = (const float*)d_in[3];
    float* out = (float*)d_out;
    ushort* wt = (ushort*)d_ws;   // 12288 bf16 = 24576 B scratch

    hipLaunchKernelGGL(wt_prep, dim3((OO * CC * KK + 255) / 256), dim3(256), 0, stream, w, wt);
    hipLaunchKernelGGL(deform_main, dim3(BB * (LL / TT)), dim3(256), 0, stream,
                       x, offs, wt, bias, out);
}